// Round 1
// baseline (2308.157 us; speedup 1.0000x reference)
//
#include <hip/hip_runtime.h>
#include <hip/hip_bf16.h>
#include <math.h>

// Problem constants (Qwen3 MoE block: B=1, S=1024, H=2048, E=64, I=768, top-k=8)
#define TT 1024
#define HH 2048
#define EE 64
#define II 768
#define TOPK 8

// GEMM tiles
#define TM 64
#define TN 64
#define TKH 32
#define APAD 4

// ---------------------------------------------------------------------------
// Kernel 0: zero output accumulator and per-expert counts
// ---------------------------------------------------------------------------
__global__ void zero_kernel(float* __restrict__ out, int n_out, int* __restrict__ counts) {
    int i = blockIdx.x * blockDim.x + threadIdx.x;
    if (i < n_out) out[i] = 0.f;
    if (i < EE) counts[i] = 0;
}

// ---------------------------------------------------------------------------
// Kernel 1: gating. One block (64 threads) per token. Thread e computes
// logit[e] = x[t,:] . gate_w[e,:]. Then thread 0 does top-8 + softmax over the
// selected logits (== softmax-then-renorm of the reference) and scatters
// (pair_index, weight) into per-expert lists via atomics.
// ---------------------------------------------------------------------------
__global__ __launch_bounds__(64) void gate_kernel(
    const float* __restrict__ x, const float* __restrict__ gw,
    int* __restrict__ counts, int* __restrict__ list_pair, float* __restrict__ list_wt)
{
    int t = blockIdx.x;
    int e = threadIdx.x;
    const float4* xr = (const float4*)(x + (size_t)t * HH);
    const float4* gr = (const float4*)(gw + (size_t)e * HH);
    float acc = 0.f;
    #pragma unroll 4
    for (int h = 0; h < HH / 4; ++h) {
        float4 a = xr[h], b = gr[h];
        acc += a.x * b.x + a.y * b.y + a.z * b.z + a.w * b.w;
    }
    __shared__ float slog[EE];
    slog[e] = acc;
    __syncthreads();
    if (e == 0) {
        float lv[TOPK];
        int li[TOPK];
        unsigned long long used = 0ULL;
        for (int k = 0; k < TOPK; ++k) {
            float best = -INFINITY;
            int bi = 0;
            for (int j = 0; j < EE; ++j) {
                if (!((used >> j) & 1ULL) && slog[j] > best) { best = slog[j]; bi = j; }
            }
            used |= 1ULL << bi;
            lv[k] = best;
            li[k] = bi;
        }
        // softmax over selected 8 (equivalent to softmax over all then renorm)
        float mx = lv[0];  // descending order -> lv[0] is max
        float w[TOPK];
        float s = 0.f;
        for (int k = 0; k < TOPK; ++k) { w[k] = __expf(lv[k] - mx); s += w[k]; }
        float inv = 1.f / s;
        for (int k = 0; k < TOPK; ++k) {
            int ex = li[k];
            int pos = atomicAdd(&counts[ex], 1);
            list_pair[ex * TT + pos] = t * TOPK + k;
            list_wt[ex * TT + pos] = w[k] * inv;
        }
    }
}

// ---------------------------------------------------------------------------
// Kernel 2: grouped up-proj SwiGLU. Block = (expert e, i-tile of 64).
// Loops over the expert's token list in tiles of 64, K over H in tiles of 32.
// act[pair, i] = topk_w * silu(x.w1) * (x.w3)   (weight folded here)
// ---------------------------------------------------------------------------
__global__ __launch_bounds__(256) void expert_up_kernel(
    const float* __restrict__ x, const float* __restrict__ w1, const float* __restrict__ w3,
    const int* __restrict__ counts, const int* __restrict__ list_pair, const float* __restrict__ list_wt,
    float* __restrict__ act)
{
    const int e  = blockIdx.x / (II / TN);
    const int nt = blockIdx.x % (II / TN);
    const int n0 = nt * TN;
    const int Ne = counts[e];
    const int tid = threadIdx.x;

    __shared__ alignas(16) float Xs[TKH][TM + APAD];   // transposed: Xs[k][m]
    __shared__ alignas(16) float W1s[TKH][TN + APAD];
    __shared__ alignas(16) float W3s[TKH][TN + APAD];
    __shared__ int   s_pair[TM];
    __shared__ float s_wt[TM];

    const int mg = tid >> 4;          // 0..15
    const int ng = tid & 15;          // 0..15
    const int mb = mg * 4, nb = ng * 4;

    for (int m0 = 0; m0 < Ne; m0 += TM) {
        if (tid < TM) {
            int m = m0 + tid;
            if (m < Ne) { s_pair[tid] = list_pair[e * TT + m]; s_wt[tid] = list_wt[e * TT + m]; }
            else        { s_pair[tid] = 0;                     s_wt[tid] = 0.f; }
        }
        float accg[4][4] = {{0.f}}, accu[4][4] = {{0.f}};

        for (int k0 = 0; k0 < HH; k0 += TKH) {
            __syncthreads();  // s_pair visible; prior compute done before LDS rewrite
            {   // stage X tile (transposed into LDS)
                int m  = tid >> 2;
                int kb = (tid & 3) * 8;
                int tok = s_pair[m] >> 3;  // padded rows read token 0 (discarded later)
                const float* src = x + (size_t)tok * HH + k0 + kb;
                float4 v0 = *(const float4*)(src);
                float4 v1 = *(const float4*)(src + 4);
                Xs[kb + 0][m] = v0.x; Xs[kb + 1][m] = v0.y; Xs[kb + 2][m] = v0.z; Xs[kb + 3][m] = v0.w;
                Xs[kb + 4][m] = v1.x; Xs[kb + 5][m] = v1.y; Xs[kb + 6][m] = v1.z; Xs[kb + 7][m] = v1.w;
            }
            {   // stage W1/W3 tiles
                int kk  = tid >> 3;
                int nbb = (tid & 7) * 8;
                size_t off = ((size_t)(e * HH + k0 + kk)) * II + n0 + nbb;
                *(float4*)&W1s[kk][nbb]     = *(const float4*)(w1 + off);
                *(float4*)&W1s[kk][nbb + 4] = *(const float4*)(w1 + off + 4);
                *(float4*)&W3s[kk][nbb]     = *(const float4*)(w3 + off);
                *(float4*)&W3s[kk][nbb + 4] = *(const float4*)(w3 + off + 4);
            }
            __syncthreads();
            #pragma unroll
            for (int kk = 0; kk < TKH; ++kk) {
                float4 a  = *(const float4*)&Xs[kk][mb];
                float4 b1 = *(const float4*)&W1s[kk][nb];
                float4 b3 = *(const float4*)&W3s[kk][nb];
                float av[4]  = {a.x, a.y, a.z, a.w};
                float b1v[4] = {b1.x, b1.y, b1.z, b1.w};
                float b3v[4] = {b3.x, b3.y, b3.z, b3.w};
                #pragma unroll
                for (int i2 = 0; i2 < 4; ++i2)
                    #pragma unroll
                    for (int j = 0; j < 4; ++j) {
                        accg[i2][j] += av[i2] * b1v[j];
                        accu[i2][j] += av[i2] * b3v[j];
                    }
            }
        }
        // epilogue: silu(g)*u * topk_weight -> act[pair, n]
        #pragma unroll
        for (int i2 = 0; i2 < 4; ++i2) {
            int m = mb + i2;
            if (m0 + m < Ne) {
                int p = s_pair[m];
                float wt = s_wt[m];
                float* dst = act + (size_t)p * II + n0 + nb;
                #pragma unroll
                for (int j = 0; j < 4; ++j) {
                    float g = accg[i2][j], u = accu[i2][j];
                    float sg = g / (1.f + __expf(-g));
                    dst[j] = wt * sg * u;
                }
            }
        }
        __syncthreads();  // protect s_pair/s_wt before next tile's list load
    }
}

// ---------------------------------------------------------------------------
// Kernel 3: grouped down-proj + combine. Block = (expert e, h-tile of 64).
// y[tok, h] += act[pair,:] . w2[e,:,h]   via fp32 atomicAdd.
// ---------------------------------------------------------------------------
#define TKI 32
__global__ __launch_bounds__(256) void expert_down_kernel(
    const float* __restrict__ act, const float* __restrict__ w2,
    const int* __restrict__ counts, const int* __restrict__ list_pair,
    float* __restrict__ out)
{
    const int e  = blockIdx.x / (HH / TN);
    const int nt = blockIdx.x % (HH / TN);
    const int n0 = nt * TN;
    const int Ne = counts[e];
    const int tid = threadIdx.x;

    __shared__ alignas(16) float As[TKI][TM + APAD];   // transposed act tile
    __shared__ alignas(16) float Bs[TKI][TN + APAD];
    __shared__ int s_pair[TM];

    const int mg = tid >> 4;
    const int ng = tid & 15;
    const int mb = mg * 4, nb = ng * 4;

    for (int m0 = 0; m0 < Ne; m0 += TM) {
        if (tid < TM) {
            int m = m0 + tid;
            s_pair[tid] = (m < Ne) ? list_pair[e * TT + m] : 0;
        }
        float acc[4][4] = {{0.f}};

        for (int k0 = 0; k0 < II; k0 += TKI) {
            __syncthreads();
            {   // stage act tile (transposed)
                int m  = tid >> 2;
                int kb = (tid & 3) * 8;
                int p = s_pair[m];
                const float* src = act + (size_t)p * II + k0 + kb;
                float4 v0 = *(const float4*)(src);
                float4 v1 = *(const float4*)(src + 4);
                As[kb + 0][m] = v0.x; As[kb + 1][m] = v0.y; As[kb + 2][m] = v0.z; As[kb + 3][m] = v0.w;
                As[kb + 4][m] = v1.x; As[kb + 5][m] = v1.y; As[kb + 6][m] = v1.z; As[kb + 7][m] = v1.w;
            }
            {   // stage w2 tile
                int kk  = tid >> 3;
                int nbb = (tid & 7) * 8;
                size_t off = ((size_t)(e * II + k0 + kk)) * HH + n0 + nbb;
                *(float4*)&Bs[kk][nbb]     = *(const float4*)(w2 + off);
                *(float4*)&Bs[kk][nbb + 4] = *(const float4*)(w2 + off + 4);
            }
            __syncthreads();
            #pragma unroll
            for (int kk = 0; kk < TKI; ++kk) {
                float4 a = *(const float4*)&As[kk][mb];
                float4 b = *(const float4*)&Bs[kk][nb];
                float av[4] = {a.x, a.y, a.z, a.w};
                float bv[4] = {b.x, b.y, b.z, b.w};
                #pragma unroll
                for (int i2 = 0; i2 < 4; ++i2)
                    #pragma unroll
                    for (int j = 0; j < 4; ++j)
                        acc[i2][j] += av[i2] * bv[j];
            }
        }
        // epilogue: atomic combine into y
        #pragma unroll
        for (int i2 = 0; i2 < 4; ++i2) {
            int m = mb + i2;
            if (m0 + m < Ne) {
                int tok = s_pair[m] >> 3;
                float* dst = out + (size_t)tok * HH + n0 + nb;
                #pragma unroll
                for (int j = 0; j < 4; ++j)
                    atomicAdd(&dst[j], acc[i2][j]);
            }
        }
        __syncthreads();
    }
}

// ---------------------------------------------------------------------------
extern "C" void kernel_launch(void* const* d_in, const int* in_sizes, int n_in,
                              void* d_out, int out_size, void* d_ws, size_t ws_size,
                              hipStream_t stream) {
    const float* x  = (const float*)d_in[0];  // [1,1024,2048]
    const float* gw = (const float*)d_in[1];  // [64,2048]
    const float* w1 = (const float*)d_in[2];  // [64,2048,768]
    const float* w3 = (const float*)d_in[3];  // [64,2048,768]
    const float* w2 = (const float*)d_in[4];  // [64,768,2048]
    float* out = (float*)d_out;               // [1,1024,2048]

    // workspace layout
    char* ws = (char*)d_ws;
    int*   counts    = (int*)ws;                            // 64 * 4 B
    int*   list_pair = (int*)(ws + 1024);                   // 64*1024*4 = 256 KB
    float* list_wt   = (float*)(ws + 1024 + 262144);        // 256 KB
    float* act       = (float*)(ws + 1024 + 2 * 262144);    // 8192*768*4 = 25.2 MB

    zero_kernel<<<(TT * HH + 255) / 256, 256, 0, stream>>>(out, TT * HH, counts);
    gate_kernel<<<TT, 64, 0, stream>>>(x, gw, counts, list_pair, list_wt);
    expert_up_kernel<<<EE * (II / TN), 256, 0, stream>>>(x, w1, w3, counts, list_pair, list_wt, act);
    expert_down_kernel<<<EE * (HH / TN), 256, 0, stream>>>(act, w2, counts, list_pair, out);
}